// Round 7
// baseline (890.979 us; speedup 1.0000x reference)
//
#include <hip/hip_runtime.h>

// QuantumQLSTM on MI355X — R18: hardened R17 (fused rec+bc). R17 failed with
// the same opaque infra error as R12; R12's byte-identical resubmit passed.
// R18 removes the one real hang risk instead of resubmitting blind:
//  (1) __launch_bounds__(512,8) forces VGPR<=64 -> 4 blocks/CU -> capacity
//      1024 resident blocks, guaranteed > grid.
//  (2) grid 515 -> 258 (each bc block copies 2 timesteps; 2k,2k+1 never
//      straddle a 32-step chunk) -> safe even at 2 blocks/CU.
//  (3) spin on thread 0 only (acquire + s_sleep), block parks at barrier,
//      one __threadfence before reads -> no 512-thread poll traffic.
//
// Theory (unchanged): bc needs only already-produced Hv[t] rows; rec makes
// them at 0.66us/step. Fusion hides bc's entire serial time + one dispatch
// gap. Prediction: rec_bc ~345-365us (WRITE_SIZE ~135MB), total ~550-575.
// If delta < 15us: bc was negligible -> invariant ~190us is harness overhead
// -> rec (339us) is the only remaining target.
//
// History: R1 4250 -> ... -> R11 632 (rec 354) -> R13 643 (NEUTRAL) ->
// R14 600 (rec 339, zx tiled) -> R16 600 (nt stores: exact null) ->
// R17 infra/hang? -> R18 (hardened fusion).

#define T_DIM 512
#define B_DIM 256
#define D_DIM 256
#define H_DIM 256
#define DH    512   // D + H
#define NG    16    // 4 gates * NQ(4)
#define XPAD  68    // Xc/Wc LDS row stride (floats): 16B-aligned, 2-way max
#define CHUNK 32    // rec->bc signal granularity
#define NCHUNK (T_DIM / CHUNK)

typedef float f32x4 __attribute__((ext_vector_type(4)));  // clang-native 16B vec

__device__ __forceinline__ float fast_sigmoid(float x) {
    return 1.0f / (1.0f + __expf(-x));
}
__device__ __forceinline__ float fast_tanh(float x) {
    // |x| <= ~2.1 here (|C| <= 0.557/(1-0.731)); exp safe
    float e = __expf(2.0f * x);
    return (e - 1.0f) / (e + 1.0f);
}
// x + dpp_mov(x): one reduction level, VALU pipe.
template <int CTRL, int RM, int BM, bool BC>
__device__ __forceinline__ float dadd(float x) {
    return x + __int_as_float(
        __builtin_amdgcn_update_dpp(0, __float_as_int(x), CTRL, RM, BM, BC));
}
// full-wave sum; result valid in lane 63
__device__ __forceinline__ float wsum(float x) {
    x = dadd<0x111, 0xf, 0xf, true >(x);   // row_shr:1
    x = dadd<0x112, 0xf, 0xf, true >(x);   // row_shr:2
    x = dadd<0x114, 0xf, 0xf, true >(x);   // row_shr:4
    x = dadd<0x118, 0xf, 0xf, true >(x);   // row_shr:8
    x = dadd<0x142, 0xa, 0xf, false>(x);   // row_bcast:15
    x = dadd<0x143, 0xc, 0xf, false>(x);   // row_bcast:31 -> lane63
    return x;
}
// lane^1 exchange on the VALU pipe: quad_perm [1,0,3,2] (replaces ds_bpermute)
__device__ __forceinline__ float dpp_xor1(float x) {
    return __int_as_float(
        __builtin_amdgcn_update_dpp(0, __float_as_int(x), 0xB1, 0xf, 0xf, true));
}
// Barrier draining ONLY the LDS pipe (no vmcnt): global ops float across steps.
__device__ __forceinline__ void lds_barrier() {
    __asm__ volatile("s_waitcnt lgkmcnt(0)\n\ts_barrier" ::: "memory");
}
// Block-wide acquire-wait on a device flag; poll traffic = 1 thread only.
__device__ __forceinline__ void wait_flag(const int* f) {
    if (threadIdx.x == 0) {
        while (__hip_atomic_load(f, __ATOMIC_ACQUIRE,
                                 __HIP_MEMORY_SCOPE_AGENT) == 0) {
            __builtin_amdgcn_s_sleep(32);   // ~2048 clk poll period
        }
    }
    __syncthreads();
    __threadfence();                        // block-wide acquire before reads
}

// -------------------- zx precompute (R14: 4x4 register tiling; unchanged
// except block 0 zeroes the rec->bc flag array)
__global__ __launch_bounds__(256) void zx_kernel(
    const float* __restrict__ x,
    const float* __restrict__ Wf, const float* __restrict__ Wi,
    const float* __restrict__ Wu, const float* __restrict__ Wo,
    const float* __restrict__ bf, const float* __restrict__ bi,
    const float* __restrict__ bu, const float* __restrict__ bo,
    const float* __restrict__ phf, const float* __restrict__ phi,
    const float* __restrict__ phu, const float* __restrict__ pho,
    float* __restrict__ zx, int* __restrict__ flags)
{
    __shared__ float Xc[256][XPAD];
    __shared__ float Wc[NG][XPAD];
    const int tid = threadIdx.x;
    const int rt  = tid >> 2;           // 0..63
    const int qt  = tid & 3;            // gate index 0..3

    if (blockIdx.x == 0 && tid < NCHUNK) flags[tid] = 0;  // visible at kernel end

    const float* bv = (qt == 0) ? bf : (qt == 1) ? bi : (qt == 2) ? bu : bo;
    const float* pv = (qt == 0) ? phf : (qt == 1) ? phi : (qt == 2) ? phu : pho;
    float acc[4][4];
    #pragma unroll
    for (int j = 0; j < 4; ++j) {
        const float bj = bv[j] + pv[j];
        acc[0][j] = bj; acc[1][j] = bj; acc[2][j] = bj; acc[3][j] = bj;
    }

    const long base = (long)blockIdx.x * 256 * D_DIM;

    for (int c = 0; c < 4; ++c) {                 // k-chunk of 64
        const int k0 = c * 64;
        #pragma unroll
        for (int it = 0; it < 16; ++it) {
            const int e = tid + it * 256;
            const int row = e >> 4, col4 = (e & 15) * 4;
            *(float4*)&Xc[row][col4] =
                *(const float4*)(x + base + (long)row * D_DIM + k0 + col4);
        }
        {
            const int q16 = tid >> 4, col4 = (tid & 15) * 4;
            const int g = q16 >> 2, qj = q16 & 3;
            const float* W = (g == 0) ? Wf : (g == 1) ? Wi : (g == 2) ? Wu : Wo;
            *(float4*)&Wc[q16][col4] = *(const float4*)(W + qj * DH + k0 + col4);
        }
        __syncthreads();

        #pragma unroll 4
        for (int kk = 0; kk < 16; ++kk) {
            const int k4 = kk * 4;
            float4 xv0 = *(float4*)&Xc[rt][k4];
            float4 xv1 = *(float4*)&Xc[rt +  64][k4];
            float4 xv2 = *(float4*)&Xc[rt + 128][k4];
            float4 xv3 = *(float4*)&Xc[rt + 192][k4];
            float4 wv0 = *(float4*)&Wc[4 * qt + 0][k4];
            float4 wv1 = *(float4*)&Wc[4 * qt + 1][k4];
            float4 wv2 = *(float4*)&Wc[4 * qt + 2][k4];
            float4 wv3 = *(float4*)&Wc[4 * qt + 3][k4];
            #pragma unroll
            for (int i = 0; i < 4; ++i) {
                const float4 xv = (i == 0) ? xv0 : (i == 1) ? xv1 : (i == 2) ? xv2 : xv3;
                acc[i][0] = fmaf(xv.x, wv0.x, fmaf(xv.y, wv0.y, fmaf(xv.z, wv0.z, fmaf(xv.w, wv0.w, acc[i][0]))));
                acc[i][1] = fmaf(xv.x, wv1.x, fmaf(xv.y, wv1.y, fmaf(xv.z, wv1.z, fmaf(xv.w, wv1.w, acc[i][1]))));
                acc[i][2] = fmaf(xv.x, wv2.x, fmaf(xv.y, wv2.y, fmaf(xv.z, wv2.z, fmaf(xv.w, wv2.w, acc[i][2]))));
                acc[i][3] = fmaf(xv.x, wv3.x, fmaf(xv.y, wv3.y, fmaf(xv.z, wv3.z, fmaf(xv.w, wv3.w, acc[i][3]))));
            }
        }
        __syncthreads();
    }

    const long orow = (long)blockIdx.x * 256;
    #pragma unroll
    for (int i = 0; i < 4; ++i) {
        *(float4*)&zx[(orow + rt + 64 * i) * NG + qt * 4] =
            make_float4(acc[i][0], acc[i][1], acc[i][2], acc[i][3]);
    }
}

// -------------------- fused sequential core + broadcast
// Grid 258. Block 0: rec (R14 path + chunk release-signals).
// Blocks 1..256: bc consumers, 2 timesteps each (tb0=2(blk-1), tb0+1 — always
// the same 32-step chunk). Block 257: tails hx=Hv[511], cx=Cfin.
// __launch_bounds__(512,8): VGPR<=64 -> 4 blocks/CU -> 1024-block residency
// capacity >> 258: every block resident regardless of dispatch order; rec
// never waits on bc; spin cannot deadlock.
__global__ __launch_bounds__(512, 8) void rec_bc_kernel(
    const float* __restrict__ Wf, const float* __restrict__ Wi,
    const float* __restrict__ Wu, const float* __restrict__ Wo,
    const float* __restrict__ zx,
    float* __restrict__ hv_tab,   // [T][H]; hv_tab[-H..-1] is a scratch pad row
    float* __restrict__ c_fin,    // [H]
    int* __restrict__ flags,      // [NCHUNK]
    float* __restrict__ out)
{
    const int tid  = threadIdx.x;          // 0..511

    if (blockIdx.x != 0) {
        // ---------------- bc consumer blocks ----------------
        const int lane = tid & 63;
        const int w    = tid >> 6;                  // wave 0..7

        if (blockIdx.x <= 256) {
            const int tb0 = 2 * ((int)blockIdx.x - 1);     // 0,2,..,510
            wait_flag(&flags[tb0 >> 5]);                   // covers tb0 and tb0+1
            #pragma unroll
            for (int tt = 0; tt < 2; ++tt) {
                const int tb = tb0 + tt;
                const f32x4 v = ((const f32x4*)(hv_tab + (long)tb * H_DIM))[lane];
                const long base = (long)tb * (B_DIM * H_DIM);
                #pragma unroll
                for (int it = 0; it < 32; ++it) {
                    const int row = w + 8 * it;            // rows 0..255
                    __builtin_nontemporal_store(
                        v, (f32x4*)(out + base + (long)row * H_DIM) + lane);
                }
            }
        } else {
            // tails: hx = Hv[T-1], cx = Cfin
            wait_flag(&flags[NCHUNK - 1]);
            const f32x4 vh = ((const f32x4*)(hv_tab + (long)(T_DIM - 1) * H_DIM))[lane];
            const f32x4 vc = ((const f32x4*)c_fin)[lane];
            const long bh = (long)T_DIM * (B_DIM * H_DIM);
            const long bc = bh + (long)B_DIM * H_DIM;
            #pragma unroll
            for (int it = 0; it < 32; ++it) {
                const int row = w + 8 * it;
                __builtin_nontemporal_store(vh, (f32x4*)(out + bh + (long)row * H_DIM) + lane);
                __builtin_nontemporal_store(vc, (f32x4*)(out + bc + (long)row * H_DIM) + lane);
            }
        }
        return;
    }

    // ---------------- rec producer block (R14 path, 339us verified) --------
    __shared__ float Hbuf[2][H_DIM];       // double-buffered Hv
    __shared__ __align__(16) float zh_s[2][8];  // [half][6 used]
    const int lane = tid & 63;
    const int wv   = tid >> 6;             // wave 0..7
    const int h    = tid >> 1;             // 0..255
    const int half = tid & 1;              // 0: f,i   1: u,o
    const int l4   = lane * 4;

    // matvec columns for waves 0..5: cols cA=2w, cB=2w+1 (c = gate*3 + (j-1))
    float4 WA = make_float4(0,0,0,0), WB = WA;
    if (wv < 6) {
        const int cA = 2 * wv, cB = cA + 1;
        const int gA = cA / 3, jA = cA % 3 + 1;
        const int gB = cB / 3, jB = cB % 3 + 1;
        const float* WgA = (gA == 0) ? Wf : (gA == 1) ? Wi : (gA == 2) ? Wu : Wo;
        const float* WgB = (gB == 0) ? Wf : (gB == 1) ? Wi : (gB == 2) ? Wu : Wo;
        WA = *(const float4*)(WgA + jA * DH + 256 + l4);
        WB = *(const float4*)(WgB + jB * DH + 256 + l4);
    }

    float C = 0.0f, Hprev = 0.0f;
    if (tid < H_DIM) Hbuf[1][tid] = 0.0f;  // Hv[-1] = 0
    __syncthreads();

    // zx register double-buffer (depth 2): thread reads its half's 2 float4
    float4 za0, za1, zb0, zb1;
    {
        const float4* p0 = (const float4*)(zx + (long)h * NG) + half * 2;
        const float4* p1 = (const float4*)(zx + ((long)B_DIM + h) * NG) + half * 2;
        za0 = p0[0]; za1 = p0[1];
        zb0 = p1[0]; zb1 = p1[1];
    }

    auto step = [&](int t, float4& z0, float4& z1) {
        // early-issue global store of Hv[t-1] (half1 lanes; acks float)
        if (half) hv_tab[(long)(t - 1) * H_DIM + h] = Hprev;

        // ---- matvec: waves 0..5, 2 columns each
        if (wv < 6) {
            const float4 Hv4 = *(const float4*)&Hbuf[(t + 1) & 1][l4];
            float pA = fmaf(WA.x, Hv4.x, fmaf(WA.y, Hv4.y, fmaf(WA.z, Hv4.z, WA.w * Hv4.w)));
            float pB = fmaf(WB.x, Hv4.x, fmaf(WB.y, Hv4.y, fmaf(WB.z, Hv4.z, WB.w * Hv4.w)));
            pA = wsum(pA);
            pB = wsum(pB);
            if (lane == 63) {
                const int cA = 2 * wv;
                zh_s[cA / 6][cA % 6]             = pA;
                zh_s[(cA + 1) / 6][(cA + 1) % 6] = pB;
            }
        }
        lds_barrier();                      // zh + Hbuf(t-1) reads done below

        // ---- gates: this thread's 2 gates (half0: f,i ; half1: u,o)
        const float4 ZA = *(const float4*)&zh_s[half][0];
        const float2 ZB = *(const float2*)&zh_s[half][4];
        const float c1 = __cosf(z0.y + ZA.x), c2 = __cosf(z0.z + ZA.y), c3 = __cosf(z0.w + ZA.z);
        const float c4 = __cosf(z1.y + ZA.w), c5 = __cosf(z1.z + ZB.x), c6 = __cosf(z1.w + ZB.y);
        const float pA = c1 * c2 * c3, pB = c4 * c5 * c6;
        float gA, gB;
        if (half == 0) { gA = fast_sigmoid(pA); gB = fast_sigmoid(pB); }   // f, i
        else           { gA = fast_tanh(pA);    gB = fast_sigmoid(pB); }   // g, o
        const float oA = dpp_xor1(gA);        // partner's first value (VALU, ~8cy)
        const float oB = dpp_xor1(gB);        // partner's second value
        const float f_ = half ? oA : gA;
        const float i_ = half ? oB : gB;
        const float g_ = half ? gA : oA;
        const float o_ = half ? gB : oB;

        // prefetch zx[t+2] (floats across steps)
        {
            const int tp = (t + 2 < T_DIM) ? (t + 2) : t;
            const float4* pp = (const float4*)(zx + ((long)tp * B_DIM + h) * NG) + half * 2;
            z0 = pp[0]; z1 = pp[1];
        }

        C = fmaf(f_, C, i_ * g_);             // both halves redundant, bit-identical
        const float Hnew = o_ * fast_tanh(C);
        if (half == 0) Hbuf[t & 1][h] = Hnew;
        Hprev = Hnew;
        lds_barrier();                        // Hbuf(t) + zh WAR for next step
    };

    for (int t = 0; t < T_DIM; t += 2) {
        step(t,     za0, za1);
        step(t + 1, zb0, zb1);
        // chunk c rows [32c,32c+31]: row 32c+31 is stored during step 32c+32,
        // so it is in flight by the bottom of iter t=32(c+1). Full release.
        if (t > 0 && (t & 31) == 0) {
            __asm__ volatile("s_waitcnt vmcnt(0)" ::: "memory");  // drain this wave's stores
            __syncthreads();                  // all waves drained
            if (tid == 0) {
                __threadfence();              // agent-scope release
                __hip_atomic_store(&flags[(t >> 5) - 1], 1,
                                   __ATOMIC_RELEASE, __HIP_MEMORY_SCOPE_AGENT);
            }
        }
    }

    if (half) {
        hv_tab[(long)(T_DIM - 1) * H_DIM + h] = Hprev;
        c_fin[h] = C;
    }
    // final chunk (rows 480..511 + c_fin): drain + release
    __asm__ volatile("s_waitcnt vmcnt(0)" ::: "memory");
    __syncthreads();
    if (tid == 0) {
        __threadfence();
        __hip_atomic_store(&flags[NCHUNK - 1], 1,
                           __ATOMIC_RELEASE, __HIP_MEMORY_SCOPE_AGENT);
    }
}

extern "C" void kernel_launch(void* const* d_in, const int* in_sizes, int n_in,
                              void* d_out, int out_size, void* d_ws, size_t ws_size,
                              hipStream_t stream) {
    (void)in_sizes; (void)n_in; (void)out_size; (void)ws_size;
    const float* x   = (const float*)d_in[0];
    const float* Wf  = (const float*)d_in[1];
    const float* bf  = (const float*)d_in[2];
    const float* phf = (const float*)d_in[3];
    const float* Wi  = (const float*)d_in[4];
    const float* bi  = (const float*)d_in[5];
    const float* phi = (const float*)d_in[6];
    const float* Wu  = (const float*)d_in[7];
    const float* bu  = (const float*)d_in[8];
    const float* phu = (const float*)d_in[9];
    const float* Wo  = (const float*)d_in[10];
    const float* bo  = (const float*)d_in[11];
    const float* pho = (const float*)d_in[12];

    float* zx     = (float*)d_ws;                          // T*B*16 f = 8.39 MB
    float* hv_pad = zx + (size_t)T_DIM * B_DIM * NG;       // 256 f scratch (t=0 store)
    float* hv_tab = hv_pad + H_DIM;                        // T*H f = 512 KB
    float* c_fin  = hv_tab + (size_t)T_DIM * H_DIM;        // H f = 1 KB
    int*   flags  = (int*)(c_fin + H_DIM);                 // NCHUNK ints

    zx_kernel<<<T_DIM, 256, 0, stream>>>(
        x, Wf, Wi, Wu, Wo, bf, bi, bu, bo, phf, phi, phu, pho, zx, flags);

    rec_bc_kernel<<<1 + B_DIM + 1, 512, 0, stream>>>(
        Wf, Wi, Wu, Wo, zx, hv_tab, c_fin, flags, (float*)d_out);
}

// Round 8
// 578.629 us; speedup vs baseline: 1.5398x; 1.5398x over previous
//
#include <hip/hip_runtime.h>

// QuantumQLSTM on MI355X — R19: revert R18 fusion (rec_bc=669 vs rec=339 —
// agent-scope fences/polling poisoned the serial loop). Back to R16 3-kernel
// structure + two rec chain cuts:
//  (1) half-wave matvec: col = half-wave (lanes 0-31 col 2w, 32-63 col 2w+1),
//      8 elem/lane, fma tree, ONE 5-level rsum32 (5 DPP vs 12).
//  (2) revolutions pre-fold: zx and recurrent W scaled by 1/2pi; gate cos =
//      v_fract + v_cos (no per-gate v_mul).
//
// R18 accounting: bc + 1 dispatch gap = 39us; zx ~40-60; fixed harness
// overhead ~160us. rec (339) is the only meaningful target left.
//
// History: R1 4250 -> ... -> R11 632 (rec 354) -> R13 643 (1-barrier+atomics:
// NEUTRAL 365) -> R14 600 (rec 339: DPP xor1, zx 4x4 tile) -> R16 600
// (nt stores: exact null) -> R18 891 (fusion: rec 2x REGRESSION) -> R19.

#define T_DIM 512
#define B_DIM 256
#define D_DIM 256
#define H_DIM 256
#define DH    512   // D + H
#define NG    16    // 4 gates * NQ(4)
#define XPAD  68    // Xc/Wc LDS row stride (floats): 16B-aligned, 2-way max
#define INV2PI 0.15915494309189535f

typedef float f32x4 __attribute__((ext_vector_type(4)));  // clang-native 16B vec

__device__ __forceinline__ float fast_sigmoid(float x) {
    return 1.0f / (1.0f + __expf(-x));
}
__device__ __forceinline__ float fast_tanh(float x) {
    // |x| <= ~2.1 here (|C| <= 0.557/(1-0.731)); exp safe
    float e = __expf(2.0f * x);
    return (e - 1.0f) / (e + 1.0f);
}
// cos(2*pi*x): input pre-scaled to revolutions; v_fract + v_cos only.
__device__ __forceinline__ float cos_rev(float x) {
#if __has_builtin(__builtin_amdgcn_fractf) && __has_builtin(__builtin_amdgcn_cosf)
    return __builtin_amdgcn_cosf(__builtin_amdgcn_fractf(x));
#else
    return __cosf(x * 6.283185307179586f);
#endif
}
// x + dpp_mov(x): one reduction level, VALU pipe.
template <int CTRL, int RM, int BM, bool BC>
__device__ __forceinline__ float dadd(float x) {
    return x + __int_as_float(
        __builtin_amdgcn_update_dpp(0, __float_as_int(x), CTRL, RM, BM, BC));
}
// 32-lane-group sum: lane31 = sum(lanes 0..31), lane63 = sum(lanes 32..63).
// (verified in R13)
__device__ __forceinline__ float rsum32(float x) {
    x = dadd<0x111, 0xf, 0xf, true >(x);   // row_shr:1
    x = dadd<0x112, 0xf, 0xf, true >(x);   // row_shr:2
    x = dadd<0x114, 0xf, 0xf, true >(x);   // row_shr:4
    x = dadd<0x118, 0xf, 0xf, true >(x);   // row_shr:8
    x = dadd<0x142, 0xa, 0xf, false>(x);   // row_bcast:15 -> lanes 31, 63
    return x;
}
// lane^1 exchange on the VALU pipe: quad_perm [1,0,3,2] (replaces ds_bpermute)
__device__ __forceinline__ float dpp_xor1(float x) {
    return __int_as_float(
        __builtin_amdgcn_update_dpp(0, __float_as_int(x), 0xB1, 0xf, 0xf, true));
}
// Barrier draining ONLY the LDS pipe (no vmcnt): global ops float across steps.
__device__ __forceinline__ void lds_barrier() {
    __asm__ volatile("s_waitcnt lgkmcnt(0)\n\ts_barrier" ::: "memory");
}

// -------------------- zx precompute (R14 4x4 register tiling; R19: outputs
// scaled to REVOLUTIONS: zx = (b_q + phi_q + x.Wx[q,:]) / 2pi)
__global__ __launch_bounds__(256) void zx_kernel(
    const float* __restrict__ x,
    const float* __restrict__ Wf, const float* __restrict__ Wi,
    const float* __restrict__ Wu, const float* __restrict__ Wo,
    const float* __restrict__ bf, const float* __restrict__ bi,
    const float* __restrict__ bu, const float* __restrict__ bo,
    const float* __restrict__ phf, const float* __restrict__ phi,
    const float* __restrict__ phu, const float* __restrict__ pho,
    float* __restrict__ zx)
{
    __shared__ float Xc[256][XPAD];
    __shared__ float Wc[NG][XPAD];
    const int tid = threadIdx.x;
    const int rt  = tid >> 2;           // 0..63
    const int qt  = tid & 3;            // gate index 0..3

    const float* bv = (qt == 0) ? bf : (qt == 1) ? bi : (qt == 2) ? bu : bo;
    const float* pv = (qt == 0) ? phf : (qt == 1) ? phi : (qt == 2) ? phu : pho;
    float acc[4][4];
    #pragma unroll
    for (int j = 0; j < 4; ++j) {
        const float bj = bv[j] + pv[j];
        acc[0][j] = bj; acc[1][j] = bj; acc[2][j] = bj; acc[3][j] = bj;
    }

    const long base = (long)blockIdx.x * 256 * D_DIM;

    for (int c = 0; c < 4; ++c) {                 // k-chunk of 64
        const int k0 = c * 64;
        #pragma unroll
        for (int it = 0; it < 16; ++it) {
            const int e = tid + it * 256;
            const int row = e >> 4, col4 = (e & 15) * 4;
            *(float4*)&Xc[row][col4] =
                *(const float4*)(x + base + (long)row * D_DIM + k0 + col4);
        }
        {
            const int q16 = tid >> 4, col4 = (tid & 15) * 4;
            const int g = q16 >> 2, qj = q16 & 3;
            const float* W = (g == 0) ? Wf : (g == 1) ? Wi : (g == 2) ? Wu : Wo;
            *(float4*)&Wc[q16][col4] = *(const float4*)(W + qj * DH + k0 + col4);
        }
        __syncthreads();

        #pragma unroll 4
        for (int kk = 0; kk < 16; ++kk) {
            const int k4 = kk * 4;
            float4 xv0 = *(float4*)&Xc[rt][k4];
            float4 xv1 = *(float4*)&Xc[rt +  64][k4];
            float4 xv2 = *(float4*)&Xc[rt + 128][k4];
            float4 xv3 = *(float4*)&Xc[rt + 192][k4];
            float4 wv0 = *(float4*)&Wc[4 * qt + 0][k4];
            float4 wv1 = *(float4*)&Wc[4 * qt + 1][k4];
            float4 wv2 = *(float4*)&Wc[4 * qt + 2][k4];
            float4 wv3 = *(float4*)&Wc[4 * qt + 3][k4];
            #pragma unroll
            for (int i = 0; i < 4; ++i) {
                const float4 xv = (i == 0) ? xv0 : (i == 1) ? xv1 : (i == 2) ? xv2 : xv3;
                acc[i][0] = fmaf(xv.x, wv0.x, fmaf(xv.y, wv0.y, fmaf(xv.z, wv0.z, fmaf(xv.w, wv0.w, acc[i][0]))));
                acc[i][1] = fmaf(xv.x, wv1.x, fmaf(xv.y, wv1.y, fmaf(xv.z, wv1.z, fmaf(xv.w, wv1.w, acc[i][1]))));
                acc[i][2] = fmaf(xv.x, wv2.x, fmaf(xv.y, wv2.y, fmaf(xv.z, wv2.z, fmaf(xv.w, wv2.w, acc[i][2]))));
                acc[i][3] = fmaf(xv.x, wv3.x, fmaf(xv.y, wv3.y, fmaf(xv.z, wv3.z, fmaf(xv.w, wv3.w, acc[i][3]))));
            }
        }
        __syncthreads();
    }

    const long orow = (long)blockIdx.x * 256;
    #pragma unroll
    for (int i = 0; i < 4; ++i) {
        *(float4*)&zx[(orow + rt + 64 * i) * NG + qt * 4] =
            make_float4(acc[i][0] * INV2PI, acc[i][1] * INV2PI,
                        acc[i][2] * INV2PI, acc[i][3] * INV2PI);
    }
}

// -------------------- sequential core: ONE block, 512 threads (8 waves)
// R19 matvec: waves 0..5, column = 2w + (lane>>5); each half-wave computes one
// full 256-dot (8 elems/lane, fma tree, single rsum32). Weights pre-scaled
// by 1/2pi so zh is in revolutions (matches zx).
__global__ __launch_bounds__(512) void rec_kernel(
    const float* __restrict__ Wf, const float* __restrict__ Wi,
    const float* __restrict__ Wu, const float* __restrict__ Wo,
    const float* __restrict__ zx,
    float* __restrict__ hv_tab,   // [T][H]; hv_tab[-H..-1] is a scratch pad row
    float* __restrict__ c_fin)    // [H]
{
    __shared__ float Hbuf[2][H_DIM];       // double-buffered Hv
    __shared__ __align__(16) float zh_s[2][8];  // [half][6 used]
    const int tid  = threadIdx.x;          // 0..511
    const int lane = tid & 63;
    const int wv   = tid >> 6;             // wave 0..7
    const int h    = tid >> 1;             // 0..255
    const int half = tid & 1;              // 0: f,i   1: u,o
    const int l31  = lane & 31;

    // matvec weights: col = 2*wv + (lane>>5); lane covers h = 4*l31..+3 and
    // h = 128+4*l31..+3. Scaled to revolutions.
    float4 W0 = make_float4(0,0,0,0), W1 = W0;
    if (wv < 6) {
        const int c = 2 * wv + (lane >> 5);
        const int g = c / 3, j = c % 3 + 1;
        const float* Wg = (g == 0) ? Wf : (g == 1) ? Wi : (g == 2) ? Wu : Wo;
        W0 = *(const float4*)(Wg + j * DH + 256 + 4 * l31);
        W1 = *(const float4*)(Wg + j * DH + 256 + 128 + 4 * l31);
        W0.x *= INV2PI; W0.y *= INV2PI; W0.z *= INV2PI; W0.w *= INV2PI;
        W1.x *= INV2PI; W1.y *= INV2PI; W1.z *= INV2PI; W1.w *= INV2PI;
    }

    float C = 0.0f, Hprev = 0.0f;
    if (tid < H_DIM) Hbuf[1][tid] = 0.0f;  // Hv[-1] = 0
    __syncthreads();

    // zx register double-buffer (depth 2): thread reads its half's 2 float4
    float4 za0, za1, zb0, zb1;
    {
        const float4* p0 = (const float4*)(zx + (long)h * NG) + half * 2;
        const float4* p1 = (const float4*)(zx + ((long)B_DIM + h) * NG) + half * 2;
        za0 = p0[0]; za1 = p0[1];
        zb0 = p1[0]; zb1 = p1[1];
    }

    auto step = [&](int t, float4& z0, float4& z1) {
        // early-issue global store of Hv[t-1] (half1 lanes; acks float)
        if (half) hv_tab[(long)(t - 1) * H_DIM + h] = Hprev;

        // ---- matvec: waves 0..5, one column per half-wave
        if (wv < 6) {
            const float4 H0 = *(const float4*)&Hbuf[(t + 1) & 1][4 * l31];
            const float4 H1 = *(const float4*)&Hbuf[(t + 1) & 1][4 * l31 + 128];
            float p0 = fmaf(W0.x, H0.x, fmaf(W0.y, H0.y, fmaf(W0.z, H0.z, W0.w * H0.w)));
            float p1 = fmaf(W1.x, H1.x, fmaf(W1.y, H1.y, fmaf(W1.z, H1.z, W1.w * H1.w)));
            float p  = rsum32(p0 + p1);
            if (l31 == 31) {                 // lanes 31 (col 2w) and 63 (col 2w+1)
                const int c = 2 * wv + (lane >> 5);
                zh_s[c / 6][c % 6] = p;
            }
        }
        lds_barrier();                      // zh + Hbuf(t-1) reads done below

        // ---- gates: this thread's 2 gates (half0: f,i ; half1: u,o)
        const float4 ZA = *(const float4*)&zh_s[half][0];
        const float2 ZB = *(const float2*)&zh_s[half][4];
        const float c1 = cos_rev(z0.y + ZA.x), c2 = cos_rev(z0.z + ZA.y), c3 = cos_rev(z0.w + ZA.z);
        const float c4 = cos_rev(z1.y + ZA.w), c5 = cos_rev(z1.z + ZB.x), c6 = cos_rev(z1.w + ZB.y);
        const float pA = c1 * c2 * c3, pB = c4 * c5 * c6;
        float gA, gB;
        if (half == 0) { gA = fast_sigmoid(pA); gB = fast_sigmoid(pB); }   // f, i
        else           { gA = fast_tanh(pA);    gB = fast_sigmoid(pB); }   // g, o
        const float oA = dpp_xor1(gA);        // partner's first value (VALU)
        const float oB = dpp_xor1(gB);        // partner's second value
        const float f_ = half ? oA : gA;
        const float i_ = half ? oB : gB;
        const float g_ = half ? gA : oA;
        const float o_ = half ? gB : oB;

        // prefetch zx[t+2] (floats across steps)
        {
            const int tp = (t + 2 < T_DIM) ? (t + 2) : t;
            const float4* pp = (const float4*)(zx + ((long)tp * B_DIM + h) * NG) + half * 2;
            z0 = pp[0]; z1 = pp[1];
        }

        C = fmaf(f_, C, i_ * g_);             // both halves redundant, bit-identical
        const float Hnew = o_ * fast_tanh(C);
        if (half == 0) Hbuf[t & 1][h] = Hnew;
        Hprev = Hnew;
        lds_barrier();                        // Hbuf(t) + zh WAR for next step
    };

    for (int t = 0; t < T_DIM; t += 2) {
        step(t,     za0, za1);
        step(t + 1, zb0, zb1);
    }

    if (half) {
        hv_tab[(long)(T_DIM - 1) * H_DIM + h] = Hprev;
        c_fin[h] = C;
    }
}

// -------------------- broadcast: out[t,b,:] = Hv[t,:]; tails hx=Hv[511], cx=Cfin
__global__ __launch_bounds__(256) void bc_kernel(
    const float* __restrict__ hv_tab, const float* __restrict__ c_fin,
    float* __restrict__ out)
{
    const int blk  = blockIdx.x;
    const int w    = threadIdx.x >> 6;
    const int lane = threadIdx.x & 63;

    const float* src;
    long base;
    int rbase;
    if (blk < 4 * T_DIM) {
        const int t = blk >> 2;
        rbase = (blk & 3) * 64;
        src = hv_tab + (long)t * H_DIM;
        base = (long)t * (B_DIM * H_DIM);
    } else {
        const int k = blk - 4 * T_DIM;        // 0..7
        rbase = (k & 3) * 64;
        src = (k < 4) ? (hv_tab + (long)(T_DIM - 1) * H_DIM) : c_fin;
        base = (long)T_DIM * (B_DIM * H_DIM) + (k < 4 ? 0 : (long)B_DIM * H_DIM);
    }
    const f32x4 v = ((const f32x4*)src)[lane];
    #pragma unroll
    for (int it = 0; it < 16; ++it) {
        const int row = rbase + w + 4 * it;
        __builtin_nontemporal_store(
            v, (f32x4*)(out + base + (long)row * H_DIM) + lane);
    }
}

extern "C" void kernel_launch(void* const* d_in, const int* in_sizes, int n_in,
                              void* d_out, int out_size, void* d_ws, size_t ws_size,
                              hipStream_t stream) {
    (void)in_sizes; (void)n_in; (void)out_size; (void)ws_size;
    const float* x   = (const float*)d_in[0];
    const float* Wf  = (const float*)d_in[1];
    const float* bf  = (const float*)d_in[2];
    const float* phf = (const float*)d_in[3];
    const float* Wi  = (const float*)d_in[4];
    const float* bi  = (const float*)d_in[5];
    const float* phi = (const float*)d_in[6];
    const float* Wu  = (const float*)d_in[7];
    const float* bu  = (const float*)d_in[8];
    const float* phu = (const float*)d_in[9];
    const float* Wo  = (const float*)d_in[10];
    const float* bo  = (const float*)d_in[11];
    const float* pho = (const float*)d_in[12];

    float* zx     = (float*)d_ws;                          // T*B*16 f = 8.39 MB
    float* hv_pad = zx + (size_t)T_DIM * B_DIM * NG;       // 256 f scratch (t=0 store)
    float* hv_tab = hv_pad + H_DIM;                        // T*H f = 512 KB
    float* c_fin  = hv_tab + (size_t)T_DIM * H_DIM;        // H f = 1 KB

    zx_kernel<<<T_DIM, 256, 0, stream>>>(
        x, Wf, Wi, Wu, Wo, bf, bi, bu, bo, phf, phi, phu, pho, zx);

    rec_kernel<<<1, 512, 0, stream>>>(
        Wf, Wi, Wu, Wo, zx, hv_tab, c_fin);

    bc_kernel<<<4 * T_DIM + 8, 256, 0, stream>>>(hv_tab, c_fin, (float*)d_out);
}